// Round 4
// baseline (917.095 us; speedup 1.0000x reference)
//
#include <hip/hip_runtime.h>
#include <hip/hip_bf16.h>

// ---------------------------------------------------------------------------
// MCT tracklet-affinity pipeline. fp32 in/out, bf16 MFMA internally.
//   g    = f - relu(f @ Wc1^T + bc1)             [192,4096] fp32 in ws
//   dist = |g_i - g_j| for upper-tri rows        [R,4096] bf16, MATERIALIZED
//   h1   = relu(dist @ W1^T + b1)                [R,2048] bf16  (pure GEMM)
//   h2   = relu(h1 @ W2^T + b2)                  [R,1024]
//   h3   = relu(h2 @ W3^T + b3)                  [R,512]
//   A[i,j]=A[j,i]=sigmoid(h3 . Ws + bs)          [192,192] fp32
// Round-4 change: dist is generated by a streaming kernel (k_distgen) instead
// of fused staging — the fused producer was latency-bound (MfmaUtil 23.7%,
// ~4650 cyc/block-iter vs 310 cyc MFMA; barrier vmcnt(0) drains defeat any
// in-loop load pipelining per m131-m141). All 3 layers are now pure
// m97-structure GEMMs (gll16 both operands, ~850-900 TF class).
// ---------------------------------------------------------------------------

typedef unsigned short u16;
typedef __attribute__((ext_vector_type(8))) short    bf16x8;
typedef __attribute__((ext_vector_type(8))) unsigned short u16x8;
typedef __attribute__((ext_vector_type(4))) float    f32x4;

#define MFMA16(a, b, c) __builtin_amdgcn_mfma_f32_16x16x32_bf16((a), (b), (c), 0, 0, 0)

#define NTRK 192
#define TRI  18528         /* 192*193/2 upper-tri rows incl diagonal */
#define TRIP 18688         /* padded to 146*128 */

__device__ __forceinline__ unsigned int pkbf(float lo, float hi) {
    __hip_bfloat162 h2 = __float22bfloat162_rn(make_float2(lo, hi));
    return *reinterpret_cast<unsigned int*>(&h2);
}
__device__ __forceinline__ void gll16(void* lds_uniform, const void* gsrc) {
    __builtin_amdgcn_global_load_lds(
        (__attribute__((address_space(1))) void*)(gsrc),
        (__attribute__((address_space(3))) void*)(lds_uniform),
        16, 0, 0);
}
// triangle row r -> (i,j), i<=j. T(i) = i*(385-i)/2. Clamped for padding rows.
__device__ __forceinline__ void tri_decode(int r, int& oi, int& oj) {
    double a = 192.5;
    int i = (int)(a - sqrt(a * a - 2.0 * (double)r));
    i = i < 0 ? 0 : (i > 191 ? 191 : i);
    while (i < 191 && (i + 1) * (385 - (i + 1)) / 2 <= r) ++i;
    while (i > 0 && i * (385 - i) / 2 > r) --i;
    int j = i + (r - i * (385 - i) / 2);
    oi = i; oj = j > 191 ? 191 : j;
}

// ---------------------------------------------------------------------------
__global__ __launch_bounds__(256)
void k_cvt(const float* __restrict__ src, u16* __restrict__ dst, int n4)
{
    int i = blockIdx.x * blockDim.x + threadIdx.x;
    const int stride = gridDim.x * blockDim.x;
    for (; i < n4; i += stride) {
        f32x4 v = ((const f32x4*)src)[i];
        ((uint2*)dst)[i] = make_uint2(pkbf(v.x, v.y), pkbf(v.z, v.w));
    }
}

// ---------------------------------------------------------------------------
// g = f - relu(fb @ Wc1b^T + bc1).  M=192,N=4096,K=4096. BM=64,BN=128,BK=64.
// ---------------------------------------------------------------------------
__global__ __launch_bounds__(256, 2)
void k_cam(const u16* __restrict__ fb, const u16* __restrict__ Wc1b,
           const float* __restrict__ bc1, const float* __restrict__ f,
           float* __restrict__ gout)
{
    __shared__ __align__(16) u16 As[64 * 64];
    __shared__ __align__(16) u16 Bs[128 * 64];
    const int t = threadIdx.x, l = t & 63, w = t >> 6;
    const int m0 = blockIdx.x * 64, n0 = blockIdx.y * 128;
    const u16* Ab = fb   + (size_t)(m0 + w * 16 + (l >> 3)) * 4096 + (l & 7) * 8;
    const u16* Bb = Wc1b + (size_t)(n0 + w * 32 + (l >> 3)) * 4096 + (l & 7) * 8;
    f32x4 acc[2][4] = {};
    const int wr = (w >> 1) * 32, wc = (w & 1) * 64;
    const int lrow = l & 15, lk = (l >> 4) * 8;

    for (int k0 = 0; k0 < 4096; k0 += 64) {
        __syncthreads();
#pragma unroll
        for (int q = 0; q < 2; ++q)
            gll16(&As[(w * 16 + q * 8) * 64], Ab + (size_t)q * 8 * 4096 + k0);
#pragma unroll
        for (int q = 0; q < 4; ++q)
            gll16(&Bs[(w * 32 + q * 8) * 64], Bb + (size_t)q * 8 * 4096 + k0);
        __syncthreads();
#pragma unroll
        for (int kk = 0; kk < 64; kk += 32) {
            bf16x8 af[2], bfr[4];
#pragma unroll
            for (int mi = 0; mi < 2; ++mi)
                af[mi] = *(const bf16x8*)&As[(wr + mi * 16 + lrow) * 64 + kk + lk];
#pragma unroll
            for (int ni = 0; ni < 4; ++ni)
                bfr[ni] = *(const bf16x8*)&Bs[(wc + ni * 16 + lrow) * 64 + kk + lk];
#pragma unroll
            for (int mi = 0; mi < 2; ++mi)
#pragma unroll
                for (int ni = 0; ni < 4; ++ni)
                    acc[mi][ni] = MFMA16(af[mi], bfr[ni], acc[mi][ni]);
        }
    }
    const int rq = (l >> 4) * 4;
#pragma unroll
    for (int ni = 0; ni < 4; ++ni) {
        const int col = n0 + wc + ni * 16 + lrow;
        const float bias = bc1[col];
#pragma unroll
        for (int mi = 0; mi < 2; ++mi) {
            const int rbase = m0 + wr + mi * 16 + rq;
#pragma unroll
            for (int v = 0; v < 4; ++v) {
                const int row = rbase + v;
                float cam = fmaxf(acc[mi][ni][v] + bias, 0.0f);
                gout[(size_t)row * 4096 + col] = f[(size_t)row * 4096 + col] - cam;
            }
        }
    }
}

// ---------------------------------------------------------------------------
// dist[r, :] = bf16(|g_i - g_j|), r = triangle row. Streaming: each thread
// produces one 16B chunk (8 bf16). grid (2, rows), 256 thr. Coalesced:
// consecutive lanes -> consecutive 16B of one row; gi/gj reads L2-resident.
// ---------------------------------------------------------------------------
__global__ __launch_bounds__(256)
void k_distgen(const float* __restrict__ g, u16* __restrict__ dist, int row0)
{
    const int r = blockIdx.y;
    const int c = blockIdx.x * 256 + threadIdx.x;       // chunk 0..511
    int pi, pj; tri_decode(row0 + r, pi, pj);
    const float* gi = g + (size_t)pi * 4096 + c * 8;
    const float* gj = g + (size_t)pj * 4096 + c * 8;
    f32x4 a0 = ((const f32x4*)gi)[0], a1 = ((const f32x4*)gi)[1];
    f32x4 b0 = ((const f32x4*)gj)[0], b1 = ((const f32x4*)gj)[1];
    uint4 o;
    o.x = pkbf(fabsf(b0.x - a0.x), fabsf(b0.y - a0.y));
    o.y = pkbf(fabsf(b0.z - a0.z), fabsf(b0.w - a0.w));
    o.z = pkbf(fabsf(b1.x - a1.x), fabsf(b1.y - a1.y));
    o.w = pkbf(fabsf(b1.z - a1.z), fabsf(b1.w - a1.w));
    *reinterpret_cast<uint4*>(dist + (size_t)r * 4096 + c * 8) = o;
}

// ---------------------------------------------------------------------------
// C = relu(A @ B^T + bias), bf16 A/B/C, fp32 bias. BM=BN=128, BK=64.
// m97 structure: gll16 both operands. grid (M/128, N/128).
// ---------------------------------------------------------------------------
__global__ __launch_bounds__(256, 2)
void k_gemm_relu(const u16* __restrict__ A, const u16* __restrict__ B,
                 const float* __restrict__ bias, u16* __restrict__ C,
                 int N, int K)
{
    __shared__ __align__(16) u16 As[128 * 64];
    __shared__ __align__(16) u16 Bs[128 * 64];
    const int t = threadIdx.x, l = t & 63, w = t >> 6;
    const int m0 = blockIdx.x * 128, n0 = blockIdx.y * 128;
    const u16* Ab = A + (size_t)(m0 + w * 32 + (l >> 3)) * K + (l & 7) * 8;
    const u16* Bb = B + (size_t)(n0 + w * 32 + (l >> 3)) * K + (l & 7) * 8;
    f32x4 acc[4][4] = {};
    const int wr = (w >> 1) * 64, wc = (w & 1) * 64;
    const int lrow = l & 15, lk = (l >> 4) * 8;

    for (int k0 = 0; k0 < K; k0 += 64) {
        __syncthreads();
#pragma unroll
        for (int q = 0; q < 4; ++q) {
            gll16(&As[(w * 32 + q * 8) * 64], Ab + (size_t)q * 8 * K + k0);
            gll16(&Bs[(w * 32 + q * 8) * 64], Bb + (size_t)q * 8 * K + k0);
        }
        __syncthreads();
#pragma unroll
        for (int kk = 0; kk < 64; kk += 32) {
            bf16x8 af[4], bfr[4];
#pragma unroll
            for (int mi = 0; mi < 4; ++mi)
                af[mi] = *(const bf16x8*)&As[(wr + mi * 16 + lrow) * 64 + kk + lk];
#pragma unroll
            for (int ni = 0; ni < 4; ++ni)
                bfr[ni] = *(const bf16x8*)&Bs[(wc + ni * 16 + lrow) * 64 + kk + lk];
#pragma unroll
            for (int mi = 0; mi < 4; ++mi)
#pragma unroll
                for (int ni = 0; ni < 4; ++ni)
                    acc[mi][ni] = MFMA16(af[mi], bfr[ni], acc[mi][ni]);
        }
    }
    const int rq = (l >> 4) * 4;
#pragma unroll
    for (int ni = 0; ni < 4; ++ni) {
        const int col = n0 + wc + ni * 16 + lrow;
        const float bv = bias[col];
#pragma unroll
        for (int mi = 0; mi < 4; ++mi) {
            const int rbase = m0 + wr + mi * 16 + rq;
#pragma unroll
            for (int v = 0; v < 4; ++v) {
                float x = fmaxf(acc[mi][ni][v] + bv, 0.0f);
                C[(size_t)(rbase + v) * N + col] = (u16)(pkbf(x, 0.0f) & 0xFFFF);
            }
        }
    }
}

// ---------------------------------------------------------------------------
// out[i,j] = out[j,i] = sigmoid(h3[r,:512] . Ws + bs). One wave per tri-row.
// ---------------------------------------------------------------------------
__global__ __launch_bounds__(256)
void k_head(const u16* __restrict__ h3, const float* __restrict__ Wsv,
            const float* __restrict__ bsv, float* __restrict__ out, int row0)
{
    const int t = threadIdx.x, l = t & 63, wv = t >> 6;
    const int rl = blockIdx.x * 4 + wv;
    if (row0 + rl >= TRI) return;
    const u16x8 hv = *(const u16x8*)(h3 + (size_t)rl * 512 + l * 8);
    const f32x4 w0 = ((const f32x4*)Wsv)[l * 2];
    const f32x4 w1 = ((const f32x4*)Wsv)[l * 2 + 1];
    float hs[8];
#pragma unroll
    for (int e = 0; e < 8; ++e) {
        union { unsigned int i; float f; } v;
        v.i = ((unsigned int)hv[e]) << 16;
        hs[e] = v.f;
    }
    float s = hs[0] * w0.x + hs[1] * w0.y + hs[2] * w0.z + hs[3] * w0.w
            + hs[4] * w1.x + hs[5] * w1.y + hs[6] * w1.z + hs[7] * w1.w;
#pragma unroll
    for (int off = 32; off >= 1; off >>= 1) s += __shfl_down(s, off, 64);
    if (l == 0) {
        float v = 1.0f / (1.0f + __expf(-(s + bsv[0])));
        int pi, pj; tri_decode(row0 + rl, pi, pj);
        out[pi * NTRK + pj] = v;
        out[pj * NTRK + pi] = v;
    }
}

// ---------------------------------------------------------------------------
extern "C" void kernel_launch(void* const* d_in, const int* in_sizes, int n_in,
                              void* d_out, int out_size, void* d_ws, size_t ws_size,
                              hipStream_t stream)
{
    const float* f   = (const float*)d_in[0];
    const float* Wc1 = (const float*)d_in[1];
    const float* bc1 = (const float*)d_in[2];
    const float* W1  = (const float*)d_in[3];
    const float* b1  = (const float*)d_in[4];
    const float* W2  = (const float*)d_in[5];
    const float* b2  = (const float*)d_in[6];
    const float* W3  = (const float*)d_in[7];
    const float* b3  = (const float*)d_in[8];
    const float* Wsv = (const float*)d_in[9];
    const float* bsv = (const float*)d_in[10];
    float* out = (float*)d_out;

    char* wsb = (char*)d_ws;
    size_t off = 0;
    u16* Wc1b = (u16*)(wsb + off); off += (size_t)4096 * 4096 * 2;
    u16* W1b  = (u16*)(wsb + off); off += (size_t)2048 * 4096 * 2;
    u16* W2b  = (u16*)(wsb + off); off += (size_t)1024 * 2048 * 2;
    u16* W3b  = (u16*)(wsb + off); off += (size_t)512  * 1024 * 2;
    u16* fb   = (u16*)(wsb + off); off += (size_t)192  * 4096 * 2;
    float* g  = (float*)(wsb + off); off += (size_t)192 * 4096 * 4;
    const size_t fixed = off;

    // chunk rows (mult of 128): need dist + h1 + h2 + h3 = R*15360 bytes
    const int Rcand[6] = {18688, 9344, 4736, 2432, 1280, 384};
    int R = 128;
    for (int c = 0; c < 6; ++c) {
        size_t need = fixed + (size_t)Rcand[c] * 15360;
        if (need <= ws_size) { R = Rcand[c]; break; }
    }
    u16* dist = (u16*)(wsb + fixed);
    u16* h1 = dist + (size_t)R * 4096;
    u16* h2 = h1 + (size_t)R * 2048;
    u16* h3 = h2 + (size_t)R * 1024;

    k_cvt<<<512, 256, 0, stream>>>(Wc1, Wc1b, 4096 * 4096 / 4);
    k_cvt<<<512, 256, 0, stream>>>(W1,  W1b,  2048 * 4096 / 4);
    k_cvt<<<256, 256, 0, stream>>>(W2,  W2b,  1024 * 2048 / 4);
    k_cvt<<<128, 256, 0, stream>>>(W3,  W3b,  512  * 1024 / 4);
    k_cvt<<<128, 256, 0, stream>>>(f,   fb,   192  * 4096 / 4);

    k_cam<<<dim3(3, 32), 256, 0, stream>>>(fb, Wc1b, bc1, f, g);

    for (int r0 = 0; r0 < TRI; r0 += R) {
        int rows = TRIP - r0; if (rows > R) rows = R;   // mult of 128
        k_distgen<<<dim3(2, rows), 256, 0, stream>>>(g, dist, r0);
        k_gemm_relu<<<dim3(rows / 128, 16), 256, 0, stream>>>(dist, W1b, b1, h1, 2048, 4096);
        k_gemm_relu<<<dim3(rows / 128, 8),  256, 0, stream>>>(h1, W2b, b2, h2, 1024, 2048);
        k_gemm_relu<<<dim3(rows / 128, 4),  256, 0, stream>>>(h2, W3b, b3, h3, 512, 1024);
        k_head<<<dim3(rows / 4), 256, 0, stream>>>(h3, Wsv, bsv, out, r0);
    }
}

// Round 5
// 856.595 us; speedup vs baseline: 1.0706x; 1.0706x over previous
//
#include <hip/hip_runtime.h>
#include <hip/hip_bf16.h>

// ---------------------------------------------------------------------------
// MCT tracklet-affinity pipeline. fp32 in/out, bf16 MFMA internally.
//   g    = f - relu(f @ Wc1^T + bc1)             [192,4096] fp32 in ws
//   dist = |g_i - g_j| for upper-tri rows        [R,4096] bf16, materialized
//   h1   = relu(dist @ W1^T + b1)                [R,2048] bf16
//   h2   = relu(h1 @ W2^T + b2)                  [R,1024]
//   h3   = relu(h2 @ W3^T + b3)                  [R,512]
//   A[i,j]=A[j,i]=sigmoid(h3 . Ws + bs)          [192,192] fp32
// Round-5 change: k_gemm_relu grid axes swapped (x = COLUMN tile, fastest).
// Round-4 had x = row tile: ~600 co-resident blocks each streamed a distinct
// 1MB A-stripe (FETCH 680 MB/dispatch, 7x ideal; MfmaUtil 29%). With x=cols
// and grid.x a multiple of 8, each XCD permanently owns the same column
// tiles (W1 B-stripes L2-resident) and the current A-stripe is shared by all
// column blocks -> A fetched ~once from HBM.
// ---------------------------------------------------------------------------

typedef unsigned short u16;
typedef __attribute__((ext_vector_type(8))) short    bf16x8;
typedef __attribute__((ext_vector_type(8))) unsigned short u16x8;
typedef __attribute__((ext_vector_type(4))) float    f32x4;

#define MFMA16(a, b, c) __builtin_amdgcn_mfma_f32_16x16x32_bf16((a), (b), (c), 0, 0, 0)

#define NTRK 192
#define TRI  18528         /* 192*193/2 upper-tri rows incl diagonal */
#define TRIP 18688         /* padded to 146*128 */

__device__ __forceinline__ unsigned int pkbf(float lo, float hi) {
    __hip_bfloat162 h2 = __float22bfloat162_rn(make_float2(lo, hi));
    return *reinterpret_cast<unsigned int*>(&h2);
}
__device__ __forceinline__ void gll16(void* lds_uniform, const void* gsrc) {
    __builtin_amdgcn_global_load_lds(
        (__attribute__((address_space(1))) void*)(gsrc),
        (__attribute__((address_space(3))) void*)(lds_uniform),
        16, 0, 0);
}
// triangle row r -> (i,j), i<=j. T(i) = i*(385-i)/2. Clamped for padding rows.
__device__ __forceinline__ void tri_decode(int r, int& oi, int& oj) {
    double a = 192.5;
    int i = (int)(a - sqrt(a * a - 2.0 * (double)r));
    i = i < 0 ? 0 : (i > 191 ? 191 : i);
    while (i < 191 && (i + 1) * (385 - (i + 1)) / 2 <= r) ++i;
    while (i > 0 && i * (385 - i) / 2 > r) --i;
    int j = i + (r - i * (385 - i) / 2);
    oi = i; oj = j > 191 ? 191 : j;
}

// ---------------------------------------------------------------------------
__global__ __launch_bounds__(256)
void k_cvt(const float* __restrict__ src, u16* __restrict__ dst, int n4)
{
    int i = blockIdx.x * blockDim.x + threadIdx.x;
    const int stride = gridDim.x * blockDim.x;
    for (; i < n4; i += stride) {
        f32x4 v = ((const f32x4*)src)[i];
        ((uint2*)dst)[i] = make_uint2(pkbf(v.x, v.y), pkbf(v.z, v.w));
    }
}

// ---------------------------------------------------------------------------
// g = f - relu(fb @ Wc1b^T + bc1).  M=192,N=4096,K=4096. BM=64,BN=128,BK=64.
// ---------------------------------------------------------------------------
__global__ __launch_bounds__(256, 2)
void k_cam(const u16* __restrict__ fb, const u16* __restrict__ Wc1b,
           const float* __restrict__ bc1, const float* __restrict__ f,
           float* __restrict__ gout)
{
    __shared__ __align__(16) u16 As[64 * 64];
    __shared__ __align__(16) u16 Bs[128 * 64];
    const int t = threadIdx.x, l = t & 63, w = t >> 6;
    const int m0 = blockIdx.x * 64, n0 = blockIdx.y * 128;
    const u16* Ab = fb   + (size_t)(m0 + w * 16 + (l >> 3)) * 4096 + (l & 7) * 8;
    const u16* Bb = Wc1b + (size_t)(n0 + w * 32 + (l >> 3)) * 4096 + (l & 7) * 8;
    f32x4 acc[2][4] = {};
    const int wr = (w >> 1) * 32, wc = (w & 1) * 64;
    const int lrow = l & 15, lk = (l >> 4) * 8;

    for (int k0 = 0; k0 < 4096; k0 += 64) {
        __syncthreads();
#pragma unroll
        for (int q = 0; q < 2; ++q)
            gll16(&As[(w * 16 + q * 8) * 64], Ab + (size_t)q * 8 * 4096 + k0);
#pragma unroll
        for (int q = 0; q < 4; ++q)
            gll16(&Bs[(w * 32 + q * 8) * 64], Bb + (size_t)q * 8 * 4096 + k0);
        __syncthreads();
#pragma unroll
        for (int kk = 0; kk < 64; kk += 32) {
            bf16x8 af[2], bfr[4];
#pragma unroll
            for (int mi = 0; mi < 2; ++mi)
                af[mi] = *(const bf16x8*)&As[(wr + mi * 16 + lrow) * 64 + kk + lk];
#pragma unroll
            for (int ni = 0; ni < 4; ++ni)
                bfr[ni] = *(const bf16x8*)&Bs[(wc + ni * 16 + lrow) * 64 + kk + lk];
#pragma unroll
            for (int mi = 0; mi < 2; ++mi)
#pragma unroll
                for (int ni = 0; ni < 4; ++ni)
                    acc[mi][ni] = MFMA16(af[mi], bfr[ni], acc[mi][ni]);
        }
    }
    const int rq = (l >> 4) * 4;
#pragma unroll
    for (int ni = 0; ni < 4; ++ni) {
        const int col = n0 + wc + ni * 16 + lrow;
        const float bias = bc1[col];
#pragma unroll
        for (int mi = 0; mi < 2; ++mi) {
            const int rbase = m0 + wr + mi * 16 + rq;
#pragma unroll
            for (int v = 0; v < 4; ++v) {
                const int row = rbase + v;
                float cam = fmaxf(acc[mi][ni][v] + bias, 0.0f);
                gout[(size_t)row * 4096 + col] = f[(size_t)row * 4096 + col] - cam;
            }
        }
    }
}

// ---------------------------------------------------------------------------
// dist[r, :] = bf16(|g_i - g_j|). One 16B chunk per thread. grid (2, rows).
// ---------------------------------------------------------------------------
__global__ __launch_bounds__(256)
void k_distgen(const float* __restrict__ g, u16* __restrict__ dist, int row0)
{
    const int r = blockIdx.y;
    const int c = blockIdx.x * 256 + threadIdx.x;       // chunk 0..511
    int pi, pj; tri_decode(row0 + r, pi, pj);
    const float* gi = g + (size_t)pi * 4096 + c * 8;
    const float* gj = g + (size_t)pj * 4096 + c * 8;
    f32x4 a0 = ((const f32x4*)gi)[0], a1 = ((const f32x4*)gi)[1];
    f32x4 b0 = ((const f32x4*)gj)[0], b1 = ((const f32x4*)gj)[1];
    uint4 o;
    o.x = pkbf(fabsf(b0.x - a0.x), fabsf(b0.y - a0.y));
    o.y = pkbf(fabsf(b0.z - a0.z), fabsf(b0.w - a0.w));
    o.z = pkbf(fabsf(b1.x - a1.x), fabsf(b1.y - a1.y));
    o.w = pkbf(fabsf(b1.z - a1.z), fabsf(b1.w - a1.w));
    *reinterpret_cast<uint4*>(dist + (size_t)r * 4096 + c * 8) = o;
}

// ---------------------------------------------------------------------------
// C = relu(A @ B^T + bias), bf16 A/B/C, fp32 bias. BM=BN=128, BK=64.
// grid (N/128, M/128): x = COLUMN tile (fast), y = row tile. With N/128 a
// multiple of 8, each XCD permanently owns its column tiles (B L2-resident)
// and all column blocks of a row-stripe share one 1MB A-stripe.
// ---------------------------------------------------------------------------
__global__ __launch_bounds__(256, 2)
void k_gemm_relu(const u16* __restrict__ A, const u16* __restrict__ B,
                 const float* __restrict__ bias, u16* __restrict__ C,
                 int N, int K)
{
    __shared__ __align__(16) u16 As[128 * 64];
    __shared__ __align__(16) u16 Bs[128 * 64];
    const int t = threadIdx.x, l = t & 63, w = t >> 6;
    const int m0 = blockIdx.y * 128, n0 = blockIdx.x * 128;   // x = column!
    const u16* Ab = A + (size_t)(m0 + w * 32 + (l >> 3)) * K + (l & 7) * 8;
    const u16* Bb = B + (size_t)(n0 + w * 32 + (l >> 3)) * K + (l & 7) * 8;
    f32x4 acc[4][4] = {};
    const int wr = (w >> 1) * 64, wc = (w & 1) * 64;
    const int lrow = l & 15, lk = (l >> 4) * 8;

    for (int k0 = 0; k0 < K; k0 += 64) {
        __syncthreads();
#pragma unroll
        for (int q = 0; q < 4; ++q) {
            gll16(&As[(w * 32 + q * 8) * 64], Ab + (size_t)q * 8 * K + k0);
            gll16(&Bs[(w * 32 + q * 8) * 64], Bb + (size_t)q * 8 * K + k0);
        }
        __syncthreads();
#pragma unroll
        for (int kk = 0; kk < 64; kk += 32) {
            bf16x8 af[4], bfr[4];
#pragma unroll
            for (int mi = 0; mi < 4; ++mi)
                af[mi] = *(const bf16x8*)&As[(wr + mi * 16 + lrow) * 64 + kk + lk];
#pragma unroll
            for (int ni = 0; ni < 4; ++ni)
                bfr[ni] = *(const bf16x8*)&Bs[(wc + ni * 16 + lrow) * 64 + kk + lk];
#pragma unroll
            for (int mi = 0; mi < 4; ++mi)
#pragma unroll
                for (int ni = 0; ni < 4; ++ni)
                    acc[mi][ni] = MFMA16(af[mi], bfr[ni], acc[mi][ni]);
        }
    }
    const int rq = (l >> 4) * 4;
#pragma unroll
    for (int ni = 0; ni < 4; ++ni) {
        const int col = n0 + wc + ni * 16 + lrow;
        const float bv = bias[col];
#pragma unroll
        for (int mi = 0; mi < 4; ++mi) {
            const int rbase = m0 + wr + mi * 16 + rq;
#pragma unroll
            for (int v = 0; v < 4; ++v) {
                float x = fmaxf(acc[mi][ni][v] + bv, 0.0f);
                C[(size_t)(rbase + v) * N + col] = (u16)(pkbf(x, 0.0f) & 0xFFFF);
            }
        }
    }
}

// ---------------------------------------------------------------------------
// out[i,j] = out[j,i] = sigmoid(h3[r,:512] . Ws + bs). One wave per tri-row.
// ---------------------------------------------------------------------------
__global__ __launch_bounds__(256)
void k_head(const u16* __restrict__ h3, const float* __restrict__ Wsv,
            const float* __restrict__ bsv, float* __restrict__ out, int row0)
{
    const int t = threadIdx.x, l = t & 63, wv = t >> 6;
    const int rl = blockIdx.x * 4 + wv;
    if (row0 + rl >= TRI) return;
    const u16x8 hv = *(const u16x8*)(h3 + (size_t)rl * 512 + l * 8);
    const f32x4 w0 = ((const f32x4*)Wsv)[l * 2];
    const f32x4 w1 = ((const f32x4*)Wsv)[l * 2 + 1];
    float hs[8];
#pragma unroll
    for (int e = 0; e < 8; ++e) {
        union { unsigned int i; float f; } v;
        v.i = ((unsigned int)hv[e]) << 16;
        hs[e] = v.f;
    }
    float s = hs[0] * w0.x + hs[1] * w0.y + hs[2] * w0.z + hs[3] * w0.w
            + hs[4] * w1.x + hs[5] * w1.y + hs[6] * w1.z + hs[7] * w1.w;
#pragma unroll
    for (int off = 32; off >= 1; off >>= 1) s += __shfl_down(s, off, 64);
    if (l == 0) {
        float v = 1.0f / (1.0f + __expf(-(s + bsv[0])));
        int pi, pj; tri_decode(row0 + rl, pi, pj);
        out[pi * NTRK + pj] = v;
        out[pj * NTRK + pi] = v;
    }
}

// ---------------------------------------------------------------------------
extern "C" void kernel_launch(void* const* d_in, const int* in_sizes, int n_in,
                              void* d_out, int out_size, void* d_ws, size_t ws_size,
                              hipStream_t stream)
{
    const float* f   = (const float*)d_in[0];
    const float* Wc1 = (const float*)d_in[1];
    const float* bc1 = (const float*)d_in[2];
    const float* W1  = (const float*)d_in[3];
    const float* b1  = (const float*)d_in[4];
    const float* W2  = (const float*)d_in[5];
    const float* b2  = (const float*)d_in[6];
    const float* W3  = (const float*)d_in[7];
    const float* b3  = (const float*)d_in[8];
    const float* Wsv = (const float*)d_in[9];
    const float* bsv = (const float*)d_in[10];
    float* out = (float*)d_out;

    char* wsb = (char*)d_ws;
    size_t off = 0;
    u16* Wc1b = (u16*)(wsb + off); off += (size_t)4096 * 4096 * 2;
    u16* W1b  = (u16*)(wsb + off); off += (size_t)2048 * 4096 * 2;
    u16* W2b  = (u16*)(wsb + off); off += (size_t)1024 * 2048 * 2;
    u16* W3b  = (u16*)(wsb + off); off += (size_t)512  * 1024 * 2;
    u16* fb   = (u16*)(wsb + off); off += (size_t)192  * 4096 * 2;
    float* g  = (float*)(wsb + off); off += (size_t)192 * 4096 * 4;
    const size_t fixed = off;

    // chunk rows (mult of 128): need dist + h1 + h2 + h3 = R*15360 bytes
    const int Rcand[6] = {18688, 9344, 4736, 2432, 1280, 384};
    int R = 128;
    for (int c = 0; c < 6; ++c) {
        size_t need = fixed + (size_t)Rcand[c] * 15360;
        if (need <= ws_size) { R = Rcand[c]; break; }
    }
    u16* dist = (u16*)(wsb + fixed);
    u16* h1 = dist + (size_t)R * 4096;
    u16* h2 = h1 + (size_t)R * 2048;
    u16* h3 = h2 + (size_t)R * 1024;

    k_cvt<<<512, 256, 0, stream>>>(Wc1, Wc1b, 4096 * 4096 / 4);
    k_cvt<<<512, 256, 0, stream>>>(W1,  W1b,  2048 * 4096 / 4);
    k_cvt<<<256, 256, 0, stream>>>(W2,  W2b,  1024 * 2048 / 4);
    k_cvt<<<128, 256, 0, stream>>>(W3,  W3b,  512  * 1024 / 4);
    k_cvt<<<128, 256, 0, stream>>>(f,   fb,   192  * 4096 / 4);

    k_cam<<<dim3(3, 32), 256, 0, stream>>>(fb, Wc1b, bc1, f, g);

    for (int r0 = 0; r0 < TRI; r0 += R) {
        int rows = TRIP - r0; if (rows > R) rows = R;   // mult of 128
        k_distgen<<<dim3(2, rows), 256, 0, stream>>>(g, dist, r0);
        k_gemm_relu<<<dim3(16, rows / 128), 256, 0, stream>>>(dist, W1b, b1, h1, 2048, 4096);
        k_gemm_relu<<<dim3(8,  rows / 128), 256, 0, stream>>>(h1, W2b, b2, h2, 1024, 2048);
        k_gemm_relu<<<dim3(4,  rows / 128), 256, 0, stream>>>(h2, W3b, b3, h3, 512, 1024);
        k_head<<<dim3(rows / 4), 256, 0, stream>>>(h3, Wsv, bsv, out, r0);
    }
}